// Round 8
// baseline (257.609 us; speedup 1.0000x reference)
//
#include <hip/hip_runtime.h>

// Problem constants: B=8, S=384, D=1024, H=16, hd=64
#define S_ 384
#define D_ 1024
#define H_ 16
#define HD_ 64

typedef short bf16x8 __attribute__((ext_vector_type(8)));
typedef float f32x4 __attribute__((ext_vector_type(4)));

#define LDS_AS3(p) ((__attribute__((address_space(3))) unsigned int*)(p))
#define GLB_AS1(p) ((const __attribute__((address_space(1))) unsigned int*)(p))

__device__ __forceinline__ unsigned short f32_to_bf16(float f) {
  unsigned u = __float_as_uint(f);
  u += 0x7FFFu + ((u >> 16) & 1u);   // round-to-nearest-even
  return (unsigned short)(u >> 16);
}
__device__ __forceinline__ float bf16_to_f32(unsigned short h) {
  return __uint_as_float(((unsigned)h) << 16);
}

// ---------------- fused prep: casts + weight transposes in one launch ------
// sections: [0,3072) x-cast | [3072,4095) rpe-cast | [4095,7167) qkv_w^T
//           | [7167,8191) out_w^T
__global__ __launch_bounds__(256) void prep_kernel(
    const float* __restrict__ x, const float* __restrict__ rpe,
    const float* __restrict__ qkv_w, const float* __restrict__ out_w,
    unsigned short* __restrict__ xb, unsigned short* __restrict__ Tb,
    unsigned short* __restrict__ Wt, unsigned short* __restrict__ Wot) {
  __shared__ float tile[32][33];
  const int bx = blockIdx.x;
  const int tid = threadIdx.x;
  if (bx < 4095) {  // element-wise casts
    const float* src = (bx < 3072) ? x : rpe;
    unsigned short* dst = (bx < 3072) ? xb : Tb;
    int i = (bx < 3072 ? bx : bx - 3072) * 256 + tid;
    float4 v = ((const float4*)src)[i];
    ushort4 o;
    o.x = f32_to_bf16(v.x); o.y = f32_to_bf16(v.y);
    o.z = f32_to_bf16(v.z); o.w = f32_to_bf16(v.w);
    ((ushort4*)dst)[i] = o;
  } else {  // transpose + cast W[K][N] -> Wt[N][K]
    const float* W; unsigned short* WT; int N, bb;
    if (bx < 7167) { W = qkv_w; WT = Wt; N = 3072; bb = bx - 4095; }
    else           { W = out_w; WT = Wot; N = 1024; bb = bx - 7167; }
    const int K = 1024;
    const int nblk = N / 32;
    const int n0 = (bb % nblk) * 32, k0 = (bb / nblk) * 32;
    const int tx = tid & 31, ty = tid >> 5;  // (32, 8)
#pragma unroll
    for (int yy = 0; yy < 32; yy += 8)
      tile[ty + yy][tx] = W[(size_t)(k0 + ty + yy) * N + n0 + tx];
    __syncthreads();
#pragma unroll
    for (int yy = 0; yy < 32; yy += 8)
      WT[(size_t)(n0 + ty + yy) * K + k0 + tx] = f32_to_bf16(tile[tx][ty + yy]);
  }
}

// ---------------- bf16 MFMA GEMM: C[M][N] = A[M][1024] * Bt[N][1024]^T ------
// 128x128 tile, 4 waves (2x2 of 64x64), BK=32, global_load_lds staging (m97).
// MODE 0: QKV epilogue (scatter to Qb/Kb bf16, V transposed to Vt, +qkv_b)
// MODE 1: out-proj epilogue (f32 to Cout, +out_b)
template <int MODE>
__global__ __launch_bounds__(256) void gemm_bt_kernel(
    const unsigned short* __restrict__ A, const unsigned short* __restrict__ Bt,
    const float* __restrict__ bias, unsigned short* __restrict__ Qb,
    unsigned short* __restrict__ Kb, unsigned short* __restrict__ Vt,
    float* __restrict__ Cout) {
  const int K = 1024;
  __shared__ __align__(16) unsigned short As[128 * 32];
  __shared__ __align__(16) unsigned short Bs[128 * 32];
  const int tid = threadIdx.x;
  const int m0 = blockIdx.x * 128, n0 = blockIdx.y * 128;
  const int wid = tid >> 6, lane = tid & 63;
  const int wr = wid >> 1, wc = wid & 1;
  const int l15 = lane & 15, lg = lane >> 4;

  const int r0 = tid >> 2, kk0 = (tid & 3) * 8;
  const int r1 = (256 + tid) >> 2, kk1 = (tid & 3) * 8;

  f32x4 acc[4][4];
#pragma unroll
  for (int m = 0; m < 4; ++m)
#pragma unroll
    for (int n = 0; n < 4; ++n) acc[m][n] = (f32x4){0.f, 0.f, 0.f, 0.f};

  for (int k0 = 0; k0 < K; k0 += 32) {
    __syncthreads();
    {
      char* asb = (char*)As + (wid << 10);
      char* bsb = (char*)Bs + (wid << 10);
      __builtin_amdgcn_global_load_lds(
          GLB_AS1(&A[(size_t)(m0 + r0) * K + k0 + kk0]), LDS_AS3(asb), 16, 0, 0);
      __builtin_amdgcn_global_load_lds(
          GLB_AS1(&Bt[(size_t)(n0 + r0) * K + k0 + kk0]), LDS_AS3(bsb), 16, 0, 0);
      __builtin_amdgcn_global_load_lds(
          GLB_AS1(&A[(size_t)(m0 + r1) * K + k0 + kk1]), LDS_AS3(asb + 4096), 16, 0, 0);
      __builtin_amdgcn_global_load_lds(
          GLB_AS1(&Bt[(size_t)(n0 + r1) * K + k0 + kk1]), LDS_AS3(bsb + 4096), 16, 0, 0);
    }
    __syncthreads();
    bf16x8 af[4], bf[4];
#pragma unroll
    for (int m = 0; m < 4; ++m)
      af[m] = *(bf16x8*)&As[(wr * 64 + m * 16 + l15) * 32 + lg * 8];
#pragma unroll
    for (int n = 0; n < 4; ++n)
      bf[n] = *(bf16x8*)&Bs[(wc * 64 + n * 16 + l15) * 32 + lg * 8];
#pragma unroll
    for (int m = 0; m < 4; ++m)
#pragma unroll
      for (int n = 0; n < 4; ++n)
        acc[m][n] =
            __builtin_amdgcn_mfma_f32_16x16x32_bf16(af[m], bf[n], acc[m][n], 0, 0, 0);
  }

  // epilogue: C/D layout col = lane&15, row = (lane>>4)*4 + reg  [HW-verified]
#pragma unroll
  for (int m = 0; m < 4; ++m) {
#pragma unroll
    for (int n = 0; n < 4; ++n) {
#pragma unroll
      for (int r = 0; r < 4; ++r) {
        int R = m0 + wr * 64 + m * 16 + lg * 4 + r;
        int c = n0 + wc * 64 + n * 16 + l15;
        float val = acc[m][n][r] + bias[c];
        if (MODE == 0) {
          int b = R / S_, s = R % S_;
          int hh = c / 192, rr = c % 192;
          int sel = rr >> 6, dd = rr & 63;
          unsigned short bv = f32_to_bf16(val);
          if (sel == 0) {
            Qb[((size_t)(b * H_ + hh) * S_ + s) * HD_ + dd] = bv;
          } else if (sel == 1) {
            Kb[((size_t)(b * H_ + hh) * S_ + s) * HD_ + dd] = bv;
          } else {
            Vt[((size_t)(b * H_ + hh) * HD_ + dd) * S_ + s] = bv;
          }
        } else {
          Cout[(size_t)R * D_ + c] = val;
        }
      }
    }
  }
}

// ---------------- XL-bias via MFMA, b-shared (2x waste) ---------------------
// grid (h=16, itile=24, jz=3), 512 threads (8 waves). Wave w: il = 2w, 2w+1;
// block z covers jH = 8z..8z+7. Table row r = il*24 + jH + (384-24h-itile)
// shared by all 8 batches -> MFMA A-rows = b. LDS transpose, coalesced writes.
__global__ __launch_bounds__(512) void bias_kernel(
    const unsigned short* __restrict__ Qb, const unsigned short* __restrict__ Tb,
    unsigned short* __restrict__ biasout) {
  __shared__ __align__(16) unsigned short tb[8][8][136];  // [wave][b][j] (+8 pad)
  const int hh = blockIdx.x;     // 0..15
  const int itile = blockIdx.y;  // 0..23
  const int jz = blockIdx.z;     // 0..2
  const int tid = threadIdx.x;
  const int wid = tid >> 6, lane = tid & 63;
  const int l15 = lane & 15, lg = lane >> 4;
  const int C = 384 - 24 * hh - itile;
  const int i0 = itile * 16;

#pragma unroll
  for (int t = 0; t < 2; ++t) {
    const int il = wid * 2 + t;
    const int i = i0 + il;
    const int b8 = l15 & 7;
    const size_t qaddr = ((size_t)(b8 * H_ + hh) * S_ + i) * HD_ + lg * 8;
    bf16x8 a0 = *(const bf16x8*)&Qb[qaddr];        // d in [0,32)
    bf16x8 a1 = *(const bf16x8*)&Qb[qaddr + 32];   // d in [32,64)
    const int rbase = il * 24 + C;
#pragma unroll
    for (int jrel = 0; jrel < 8; ++jrel) {
      const int jH = jz * 8 + jrel;
      const unsigned short* trow = Tb + (size_t)(rbase + jH) * D_;
      bf16x8 b0 = *(const bf16x8*)&trow[l15 * 64 + lg * 8];
      bf16x8 b1 = *(const bf16x8*)&trow[l15 * 64 + 32 + lg * 8];
      f32x4 d = {0.f, 0.f, 0.f, 0.f};
      d = __builtin_amdgcn_mfma_f32_16x16x32_bf16(a0, b0, d, 0, 0, 0);
      d = __builtin_amdgcn_mfma_f32_16x16x32_bf16(a1, b1, d, 0, 0, 0);
      if (lg < 2) {  // D rows = b = lg*4+rr (valid b<8); cols = jL = l15
#pragma unroll
        for (int rr = 0; rr < 4; ++rr)
          tb[wid][lg * 4 + rr][jrel * 16 + l15] = f32_to_bf16(d[rr]);
      }
    }
    __syncthreads();
    {  // coalesced write: lane -> (b = lane>>3, 32B j-segment)
      const int b = lane >> 3;
      const int jseg = (lane & 7) * 16;
      uint4 v0 = *(const uint4*)&tb[wid][b][jseg];
      uint4 v1 = *(const uint4*)&tb[wid][b][jseg + 8];
      unsigned short* dst =
          &biasout[(((size_t)(b * H_ + hh)) * S_ + i) * S_ + jz * 128 + jseg];
      *(uint4*)dst = v0;
      *(uint4*)&dst[8] = v1;
    }
    __syncthreads();  // tb reused by next t
  }
}

// ---------------- fused QK^T(+bias) -> softmax -> PV, 32-row blocks ---------
// grid (b*h=128, it32=12), 512 threads (8 waves). Same 52KB LDS per block as
// the 256-thread version (3 blocks/CU) but 24 waves/CU and ~half the serial
// critical path. Row stride 404 f32 (808B): PV bf16 reads conflict-free,
// QK/softmax <=2-way (free). Probs packed bf16 in-place (ushort j -> f32 j/2).
__global__ __launch_bounds__(512) void attn3_kernel(
    const unsigned short* __restrict__ Qb, const unsigned short* __restrict__ Kb,
    const unsigned short* __restrict__ Vt, const unsigned short* __restrict__ Bias,
    float* __restrict__ attn_out, unsigned short* __restrict__ Vals) {
  __shared__ float lgs[32][404];
  const int bh = blockIdx.x;
  const int it32 = blockIdx.y;
  const int i0 = it32 * 32;
  const size_t base = (size_t)bh * (S_ * HD_);
  const int tid = threadIdx.x, wid = tid >> 6, lane = tid & 63;
  const int l15 = lane & 15, lg = lane >> 4;

  // Q A-frags for both 16-row tiles: row = il (l15), k = d
  bf16x8 qa[2][2];
#pragma unroll
  for (int mt = 0; mt < 2; ++mt) {
    const size_t qaddr = base + (size_t)(i0 + mt * 16 + l15) * HD_ + lg * 8;
    qa[mt][0] = *(const bf16x8*)&Qb[qaddr];
    qa[mt][1] = *(const bf16x8*)&Qb[qaddr + 32];
  }

  // stage bias tile (32x384 bf16) -> lgs f32 (coalesced)
  {
    const unsigned short* bsrc = Bias + ((size_t)bh * S_ + i0) * S_;
#pragma unroll
    for (int it = 0; it < 3; ++it) {
      int e = it * 512 + tid;  // 1536 chunks of 8 elems
      int row = e / 48, c8 = (e % 48) * 8;
      ushort4 v0 = *(const ushort4*)&bsrc[(size_t)row * S_ + c8];
      ushort4 v1 = *(const ushort4*)&bsrc[(size_t)row * S_ + c8 + 4];
      float4 f0 = {bf16_to_f32(v0.x), bf16_to_f32(v0.y),
                   bf16_to_f32(v0.z), bf16_to_f32(v0.w)};
      float4 f1 = {bf16_to_f32(v1.x), bf16_to_f32(v1.y),
                   bf16_to_f32(v1.z), bf16_to_f32(v1.w)};
      *(float4*)&lgs[row][c8] = f0;
      *(float4*)&lgs[row][c8 + 4] = f1;
    }
  }
  __syncthreads();

  // ---- QK^T: wave covers jH = wid*3..+2; K-frags feed both row-tiles
#pragma unroll
  for (int t = 0; t < 3; ++t) {
    const int j0 = (wid * 3 + t) * 16;
    const size_t kaddr = base + (size_t)(j0 + l15) * HD_ + lg * 8;
    bf16x8 kb0 = *(const bf16x8*)&Kb[kaddr];
    bf16x8 kb1 = *(const bf16x8*)&Kb[kaddr + 32];
#pragma unroll
    for (int mt = 0; mt < 2; ++mt) {
      f32x4 d = {0.f, 0.f, 0.f, 0.f};
      d = __builtin_amdgcn_mfma_f32_16x16x32_bf16(qa[mt][0], kb0, d, 0, 0, 0);
      d = __builtin_amdgcn_mfma_f32_16x16x32_bf16(qa[mt][1], kb1, d, 0, 0, 0);
#pragma unroll
      for (int rr = 0; rr < 4; ++rr) {  // D: row = lg*4+rr, col = l15
        const int il = mt * 16 + lg * 4 + rr;
        lgs[il][j0 + l15] = fmaf(d[rr], 0.125f, lgs[il][j0 + l15]);
      }
    }
  }
  __syncthreads();

  // ---- softmax: all 32 rows in one pass (16 lanes/row); in-place bf16 pack
  unsigned short* us = (unsigned short*)&lgs[0][0];
  {
    const int row = tid >> 4;
    const int l16 = tid & 15;
    float m = -1e30f;
    for (int j = l16; j < S_; j += 16) m = fmaxf(m, lgs[row][j]);
#pragma unroll
    for (int o = 8; o; o >>= 1) m = fmaxf(m, __shfl_xor(m, o, 16));
    float s = 0.f;
    for (int j = l16; j < S_; j += 16) {
      float e = __expf(lgs[row][j] - m);
      lgs[row][j] = e;
      s += e;
    }
#pragma unroll
    for (int o = 8; o; o >>= 1) s += __shfl_xor(s, o, 16);
    const float inv = 1.0f / s;
    float* ao = attn_out + ((size_t)bh * S_ + i0 + row) * S_;
    for (int j = l16; j < S_; j += 16) {
      float pv = lgs[row][j] * inv;
      ao[j] = pv;
      us[row * 808 + j] = f32_to_bf16(pv);  // clobbers f32 col j/2 (consumed)
    }
  }
  __syncthreads();

  // ---- PV: wave -> (mt = wid>>2, d0 = (wid&3)*16); 1 MFMA per kc
  {
    const int mt = wid >> 2;
    const int d0 = (wid & 3) * 16;
    f32x4 acc = {0.f, 0.f, 0.f, 0.f};
#pragma unroll
    for (int kc = 0; kc < 12; ++kc) {
      bf16x8 vb =
          *(const bf16x8*)&Vt[base + (size_t)(d0 + l15) * S_ + kc * 32 + lg * 8];
      bf16x8 pa =
          *(const bf16x8*)&us[(size_t)(mt * 16 + l15) * 808 + kc * 32 + lg * 8];
      acc = __builtin_amdgcn_mfma_f32_16x16x32_bf16(pa, vb, acc, 0, 0, 0);
    }
    const int b = bh >> 4, hh = bh & 15;
#pragma unroll
    for (int rr = 0; rr < 4; ++rr) {
      const int il = mt * 16 + lg * 4 + rr;
      Vals[((size_t)(b * S_ + i0 + il)) * D_ + hh * HD_ + d0 + l15] =
          f32_to_bf16(acc[rr]);
    }
  }
}

// ---------------------------------------------------------------------------
extern "C" void kernel_launch(void* const* d_in, const int* in_sizes, int n_in,
                              void* d_out, int out_size, void* d_ws,
                              size_t ws_size, hipStream_t stream) {
  (void)in_sizes; (void)n_in; (void)out_size; (void)ws_size;
  const float* x     = (const float*)d_in[0];  // (8,384,1024)
  const float* qkv_w = (const float*)d_in[1];  // (1024,3072)
  const float* qkv_b = (const float*)d_in[2];  // (3072,)
  const float* out_w = (const float*)d_in[3];  // (1024,1024)
  const float* out_b = (const float*)d_in[4];  // (1024,)
  const float* rpe   = (const float*)d_in[5];  // (1023,1024)

  float* out  = (float*)d_out;        // 3145728 f32
  float* attn = out + 3145728;        // 18874368 f32 (probs, written by attn3)

  unsigned short* ws  = (unsigned short*)d_ws;
  unsigned short* xb  = ws;                 // 3072*1024
  unsigned short* Wt  = xb + 3145728;       // 3072*1024 (qkv_w^T)
  unsigned short* Wot = Wt + 3145728;       // 1024*1024 (out_w^T)
  unsigned short* Tb  = Wot + 1048576;      // 1023*1024
  unsigned short* Qb  = Tb + 1047552;       // (b,h,s,hd)
  unsigned short* Kb  = Qb + 3145728;       // (b,h,s,hd)
  unsigned short* Vt  = Kb + 3145728;       // (b,h,hd,s)  transposed V
  unsigned short* Vals = Vt + 3145728;      // (b*s, 1024) bf16
  unsigned short* Bias = Vals + 3145728;    // (b,h,s,s) bf16 staged XL bias

  // 1) fused prep (casts + transposes)
  prep_kernel<<<8191, 256, 0, stream>>>(x, rpe, qkv_w, out_w, xb, Tb, Wt, Wot);

  // 2) QKV projection (M=3072, N=3072); V written transposed
  gemm_bt_kernel<0><<<dim3(24, 24), 256, 0, stream>>>(xb, Wt, qkv_b, Qb, Kb, Vt, nullptr);

  // 3) XL relative bias (MFMA, b-shared) -> bf16 workspace
  bias_kernel<<<dim3(16, 24, 3), 512, 0, stream>>>(Qb, Tb, Bias);

  // 4) fused QK^T(+bias) -> softmax -> PV, 32 rows/block, 8 waves
  attn3_kernel<<<dim3(128, 12), 512, 0, stream>>>(Qb, Kb, Vt, Bias, attn, Vals);

  // 5) output projection (M=3072, N=1024)
  gemm_bt_kernel<1><<<dim3(24, 8), 256, 0, stream>>>(Vals, Wot, out_b, nullptr, nullptr, nullptr, out);
}

// Round 10
// 254.813 us; speedup vs baseline: 1.0110x; 1.0110x over previous
//
#include <hip/hip_runtime.h>

// Problem constants: B=8, S=384, D=1024, H=16, hd=64
#define S_ 384
#define D_ 1024
#define H_ 16
#define HD_ 64

typedef short bf16x8 __attribute__((ext_vector_type(8)));
typedef float f32x4 __attribute__((ext_vector_type(4)));

#define LDS_AS3(p) ((__attribute__((address_space(3))) unsigned int*)(p))
#define GLB_AS1(p) ((const __attribute__((address_space(1))) unsigned int*)(p))

__device__ __forceinline__ unsigned short f32_to_bf16(float f) {
  unsigned u = __float_as_uint(f);
  u += 0x7FFFu + ((u >> 16) & 1u);   // round-to-nearest-even
  return (unsigned short)(u >> 16);
}
__device__ __forceinline__ float bf16_to_f32(unsigned short h) {
  return __uint_as_float(((unsigned)h) << 16);
}

// ---------------- fused prep: casts + weight transposes in one launch ------
// sections: [0,3072) x-cast | [3072,4095) rpe-cast | [4095,7167) qkv_w^T
//           | [7167,8191) out_w^T
__global__ __launch_bounds__(256) void prep_kernel(
    const float* __restrict__ x, const float* __restrict__ rpe,
    const float* __restrict__ qkv_w, const float* __restrict__ out_w,
    unsigned short* __restrict__ xb, unsigned short* __restrict__ Tb,
    unsigned short* __restrict__ Wt, unsigned short* __restrict__ Wot) {
  __shared__ float tile[32][33];
  const int bx = blockIdx.x;
  const int tid = threadIdx.x;
  if (bx < 4095) {  // element-wise casts
    const float* src = (bx < 3072) ? x : rpe;
    unsigned short* dst = (bx < 3072) ? xb : Tb;
    int i = (bx < 3072 ? bx : bx - 3072) * 256 + tid;
    float4 v = ((const float4*)src)[i];
    ushort4 o;
    o.x = f32_to_bf16(v.x); o.y = f32_to_bf16(v.y);
    o.z = f32_to_bf16(v.z); o.w = f32_to_bf16(v.w);
    ((ushort4*)dst)[i] = o;
  } else {  // transpose + cast W[K][N] -> Wt[N][K]
    const float* W; unsigned short* WT; int N, bb;
    if (bx < 7167) { W = qkv_w; WT = Wt; N = 3072; bb = bx - 4095; }
    else           { W = out_w; WT = Wot; N = 1024; bb = bx - 7167; }
    const int K = 1024;
    const int nblk = N / 32;
    const int n0 = (bb % nblk) * 32, k0 = (bb / nblk) * 32;
    const int tx = tid & 31, ty = tid >> 5;  // (32, 8)
#pragma unroll
    for (int yy = 0; yy < 32; yy += 8)
      tile[ty + yy][tx] = W[(size_t)(k0 + ty + yy) * N + n0 + tx];
    __syncthreads();
#pragma unroll
    for (int yy = 0; yy < 32; yy += 8)
      WT[(size_t)(n0 + ty + yy) * K + k0 + tx] = f32_to_bf16(tile[tx][ty + yy]);
  }
}

// ---------------- bf16 MFMA GEMM: C[M][N] = A[M][1024] * Bt[N][1024]^T ------
// 128x128 tile, 4 waves (2x2 of 64x64), BK=32, global_load_lds staging (m97).
// MODE 0: QKV epilogue (scatter to Qb/Kb bf16, V transposed to Vt, +qkv_b;
//         K pre-scaled by 1/8 so attn drops the logit scale)
// MODE 1: out-proj epilogue (f32 to Cout, +out_b)
template <int MODE>
__global__ __launch_bounds__(256) void gemm_bt_kernel(
    const unsigned short* __restrict__ A, const unsigned short* __restrict__ Bt,
    const float* __restrict__ bias, unsigned short* __restrict__ Qb,
    unsigned short* __restrict__ Kb, unsigned short* __restrict__ Vt,
    float* __restrict__ Cout) {
  const int K = 1024;
  __shared__ __align__(16) unsigned short As[128 * 32];
  __shared__ __align__(16) unsigned short Bs[128 * 32];
  const int tid = threadIdx.x;
  const int m0 = blockIdx.x * 128, n0 = blockIdx.y * 128;
  const int wid = tid >> 6, lane = tid & 63;
  const int wr = wid >> 1, wc = wid & 1;
  const int l15 = lane & 15, lg = lane >> 4;

  const int r0 = tid >> 2, kk0 = (tid & 3) * 8;
  const int r1 = (256 + tid) >> 2, kk1 = (tid & 3) * 8;

  f32x4 acc[4][4];
#pragma unroll
  for (int m = 0; m < 4; ++m)
#pragma unroll
    for (int n = 0; n < 4; ++n) acc[m][n] = (f32x4){0.f, 0.f, 0.f, 0.f};

  for (int k0 = 0; k0 < K; k0 += 32) {
    __syncthreads();
    {
      char* asb = (char*)As + (wid << 10);
      char* bsb = (char*)Bs + (wid << 10);
      __builtin_amdgcn_global_load_lds(
          GLB_AS1(&A[(size_t)(m0 + r0) * K + k0 + kk0]), LDS_AS3(asb), 16, 0, 0);
      __builtin_amdgcn_global_load_lds(
          GLB_AS1(&Bt[(size_t)(n0 + r0) * K + k0 + kk0]), LDS_AS3(bsb), 16, 0, 0);
      __builtin_amdgcn_global_load_lds(
          GLB_AS1(&A[(size_t)(m0 + r1) * K + k0 + kk1]), LDS_AS3(asb + 4096), 16, 0, 0);
      __builtin_amdgcn_global_load_lds(
          GLB_AS1(&Bt[(size_t)(n0 + r1) * K + k0 + kk1]), LDS_AS3(bsb + 4096), 16, 0, 0);
    }
    __syncthreads();
    bf16x8 af[4], bf[4];
#pragma unroll
    for (int m = 0; m < 4; ++m)
      af[m] = *(bf16x8*)&As[(wr * 64 + m * 16 + l15) * 32 + lg * 8];
#pragma unroll
    for (int n = 0; n < 4; ++n)
      bf[n] = *(bf16x8*)&Bs[(wc * 64 + n * 16 + l15) * 32 + lg * 8];
#pragma unroll
    for (int m = 0; m < 4; ++m)
#pragma unroll
      for (int n = 0; n < 4; ++n)
        acc[m][n] =
            __builtin_amdgcn_mfma_f32_16x16x32_bf16(af[m], bf[n], acc[m][n], 0, 0, 0);
  }

  // epilogue: C/D layout col = lane&15, row = (lane>>4)*4 + reg  [HW-verified]
#pragma unroll
  for (int m = 0; m < 4; ++m) {
#pragma unroll
    for (int n = 0; n < 4; ++n) {
#pragma unroll
      for (int r = 0; r < 4; ++r) {
        int R = m0 + wr * 64 + m * 16 + lg * 4 + r;
        int c = n0 + wc * 64 + n * 16 + l15;
        float val = acc[m][n][r] + bias[c];
        if (MODE == 0) {
          int b = R / S_, s = R % S_;
          int hh = c / 192, rr = c % 192;
          int sel = rr >> 6, dd = rr & 63;
          if (sel == 0) {
            Qb[((size_t)(b * H_ + hh) * S_ + s) * HD_ + dd] = f32_to_bf16(val);
          } else if (sel == 1) {
            // pre-scale K by 1/8: logits = q·(k/8) + bias
            Kb[((size_t)(b * H_ + hh) * S_ + s) * HD_ + dd] =
                f32_to_bf16(val * 0.125f);
          } else {
            Vt[((size_t)(b * H_ + hh) * HD_ + dd) * S_ + s] = f32_to_bf16(val);
          }
        } else {
          Cout[(size_t)R * D_ + c] = val;
        }
      }
    }
  }
}

// ---------------- XL-bias via MFMA, b-shared (2x waste) ---------------------
// grid (h=16, itile=24, jz=3), 512 threads (8 waves). Wave w: il = 2w, 2w+1;
// block z covers jH = 8z..8z+7. Table row r = il*24 + jH + (384-24h-itile)
// shared by all 8 batches -> MFMA A-rows = b. LDS transpose, coalesced writes.
__global__ __launch_bounds__(512) void bias_kernel(
    const unsigned short* __restrict__ Qb, const unsigned short* __restrict__ Tb,
    unsigned short* __restrict__ biasout) {
  __shared__ __align__(16) unsigned short tb[8][8][136];  // [wave][b][j] (+8 pad)
  const int hh = blockIdx.x;     // 0..15
  const int itile = blockIdx.y;  // 0..23
  const int jz = blockIdx.z;     // 0..2
  const int tid = threadIdx.x;
  const int wid = tid >> 6, lane = tid & 63;
  const int l15 = lane & 15, lg = lane >> 4;
  const int C = 384 - 24 * hh - itile;
  const int i0 = itile * 16;

#pragma unroll
  for (int t = 0; t < 2; ++t) {
    const int il = wid * 2 + t;
    const int i = i0 + il;
    const int b8 = l15 & 7;
    const size_t qaddr = ((size_t)(b8 * H_ + hh) * S_ + i) * HD_ + lg * 8;
    bf16x8 a0 = *(const bf16x8*)&Qb[qaddr];        // d in [0,32)
    bf16x8 a1 = *(const bf16x8*)&Qb[qaddr + 32];   // d in [32,64)
    const int rbase = il * 24 + C;
#pragma unroll
    for (int jrel = 0; jrel < 8; ++jrel) {
      const int jH = jz * 8 + jrel;
      const unsigned short* trow = Tb + (size_t)(rbase + jH) * D_;
      bf16x8 b0 = *(const bf16x8*)&trow[l15 * 64 + lg * 8];
      bf16x8 b1 = *(const bf16x8*)&trow[l15 * 64 + 32 + lg * 8];
      f32x4 d = {0.f, 0.f, 0.f, 0.f};
      d = __builtin_amdgcn_mfma_f32_16x16x32_bf16(a0, b0, d, 0, 0, 0);
      d = __builtin_amdgcn_mfma_f32_16x16x32_bf16(a1, b1, d, 0, 0, 0);
      if (lg < 2) {  // D rows = b = lg*4+rr (valid b<8); cols = jL = l15
#pragma unroll
        for (int rr = 0; rr < 4; ++rr)
          tb[wid][lg * 4 + rr][jrel * 16 + l15] = f32_to_bf16(d[rr]);
      }
    }
    __syncthreads();
    {  // coalesced write: lane -> (b = lane>>3, 32B j-segment)
      const int b = lane >> 3;
      const int jseg = (lane & 7) * 16;
      uint4 v0 = *(const uint4*)&tb[wid][b][jseg];
      uint4 v1 = *(const uint4*)&tb[wid][b][jseg + 8];
      unsigned short* dst =
          &biasout[(((size_t)(b * H_ + hh)) * S_ + i) * S_ + jz * 128 + jseg];
      *(uint4*)dst = v0;
      *(uint4*)&dst[8] = v1;
    }
    __syncthreads();  // tb reused by next t
  }
}

// ---------------- fused QK^T(+bias) -> softmax -> PV, 32-row blocks ---------
// grid (b*h=128, it32=12), 512 threads (8 waves). Softmax: max-pass,
// exp+sum-pass (strided LDS), then a separate fully-coalesced phase that
// normalizes, streams float4 probs to global (contiguous 192KB block) and
// packs bf16 probs in-place (read-ahead-of-write safe per wave iteration).
__global__ __launch_bounds__(512) void attn3_kernel(
    const unsigned short* __restrict__ Qb, const unsigned short* __restrict__ Kb,
    const unsigned short* __restrict__ Vt, const unsigned short* __restrict__ Bias,
    float* __restrict__ attn_out, unsigned short* __restrict__ Vals) {
  __shared__ float lgs[32][404];
  __shared__ float invs[32];
  const int bh = blockIdx.x;
  const int it32 = blockIdx.y;
  const int i0 = it32 * 32;
  const size_t base = (size_t)bh * (S_ * HD_);
  const int tid = threadIdx.x, wid = tid >> 6, lane = tid & 63;
  const int l15 = lane & 15, lg = lane >> 4;

  // Q A-frags for both 16-row tiles: row = il (l15), k = d
  bf16x8 qa[2][2];
#pragma unroll
  for (int mt = 0; mt < 2; ++mt) {
    const size_t qaddr = base + (size_t)(i0 + mt * 16 + l15) * HD_ + lg * 8;
    qa[mt][0] = *(const bf16x8*)&Qb[qaddr];
    qa[mt][1] = *(const bf16x8*)&Qb[qaddr + 32];
  }

  // stage bias tile (32x384 bf16) -> lgs f32 (coalesced)
  {
    const unsigned short* bsrc = Bias + ((size_t)bh * S_ + i0) * S_;
#pragma unroll
    for (int it = 0; it < 3; ++it) {
      int e = it * 512 + tid;  // 1536 chunks of 8 elems
      int row = e / 48, c8 = (e % 48) * 8;
      ushort4 v0 = *(const ushort4*)&bsrc[(size_t)row * S_ + c8];
      ushort4 v1 = *(const ushort4*)&bsrc[(size_t)row * S_ + c8 + 4];
      float4 f0 = {bf16_to_f32(v0.x), bf16_to_f32(v0.y),
                   bf16_to_f32(v0.z), bf16_to_f32(v0.w)};
      float4 f1 = {bf16_to_f32(v1.x), bf16_to_f32(v1.y),
                   bf16_to_f32(v1.z), bf16_to_f32(v1.w)};
      *(float4*)&lgs[row][c8] = f0;
      *(float4*)&lgs[row][c8 + 4] = f1;
    }
  }
  __syncthreads();

  // ---- QK^T: wave covers jH = wid*3..+2; K pre-scaled, so plain add
#pragma unroll
  for (int t = 0; t < 3; ++t) {
    const int j0 = (wid * 3 + t) * 16;
    const size_t kaddr = base + (size_t)(j0 + l15) * HD_ + lg * 8;
    bf16x8 kb0 = *(const bf16x8*)&Kb[kaddr];
    bf16x8 kb1 = *(const bf16x8*)&Kb[kaddr + 32];
#pragma unroll
    for (int mt = 0; mt < 2; ++mt) {
      f32x4 d = {0.f, 0.f, 0.f, 0.f};
      d = __builtin_amdgcn_mfma_f32_16x16x32_bf16(qa[mt][0], kb0, d, 0, 0, 0);
      d = __builtin_amdgcn_mfma_f32_16x16x32_bf16(qa[mt][1], kb1, d, 0, 0, 0);
#pragma unroll
      for (int rr = 0; rr < 4; ++rr) {  // D: row = lg*4+rr, col = l15
        const int il = mt * 16 + lg * 4 + rr;
        lgs[il][j0 + l15] += d[rr];
      }
    }
  }
  __syncthreads();

  // ---- softmax passes 1-2: max, exp+sum (strided, 16 lanes/row)
  {
    const int row = tid >> 4;
    const int l16 = tid & 15;
    float m = -1e30f;
    for (int j = l16; j < S_; j += 16) m = fmaxf(m, lgs[row][j]);
#pragma unroll
    for (int o = 8; o; o >>= 1) m = fmaxf(m, __shfl_xor(m, o, 16));
    float s = 0.f;
    for (int j = l16; j < S_; j += 16) {
      float e = __expf(lgs[row][j] - m);
      lgs[row][j] = e;
      s += e;
    }
#pragma unroll
    for (int o = 8; o; o >>= 1) s += __shfl_xor(s, o, 16);
    if (l16 == 0) invs[row] = 1.0f / s;
  }
  __syncthreads();

  // ---- phase 3: coalesced normalize + f32 stream-out + in-place bf16 pack
  unsigned short* us = (unsigned short*)&lgs[0][0];
  {
    const int row = tid >> 4;
    const int l16 = tid & 15;
    const float inv = invs[row];
    float* ao = attn_out + ((size_t)bh * S_ + i0 + row) * S_;
#pragma unroll
    for (int k = 0; k < 6; ++k) {
      const int j4 = (k * 16 + l16) * 4;
      float4 v = *(const float4*)&lgs[row][j4];
      v.x *= inv; v.y *= inv; v.z *= inv; v.w *= inv;
      *(float4*)&ao[j4] = v;
      ushort4 pk = {f32_to_bf16(v.x), f32_to_bf16(v.y),
                    f32_to_bf16(v.z), f32_to_bf16(v.w)};
      *(ushort4*)&us[row * 808 + j4] = pk;  // clobbers f32 cols < read frontier
    }
  }
  __syncthreads();

  // ---- PV: wave -> (mt = wid>>2, d0 = (wid&3)*16); 1 MFMA per kc
  {
    const int mt = wid >> 2;
    const int d0 = (wid & 3) * 16;
    f32x4 acc = {0.f, 0.f, 0.f, 0.f};
#pragma unroll
    for (int kc = 0; kc < 12; ++kc) {
      bf16x8 vb =
          *(const bf16x8*)&Vt[base + (size_t)(d0 + l15) * S_ + kc * 32 + lg * 8];
      bf16x8 pa =
          *(const bf16x8*)&us[(size_t)(mt * 16 + l15) * 808 + kc * 32 + lg * 8];
      acc = __builtin_amdgcn_mfma_f32_16x16x32_bf16(pa, vb, acc, 0, 0, 0);
    }
    const int b = bh >> 4, hh = bh & 15;
#pragma unroll
    for (int rr = 0; rr < 4; ++rr) {
      const int il = mt * 16 + lg * 4 + rr;
      Vals[((size_t)(b * S_ + i0 + il)) * D_ + hh * HD_ + d0 + l15] =
          f32_to_bf16(acc[rr]);
    }
  }
}

// ---------------------------------------------------------------------------
extern "C" void kernel_launch(void* const* d_in, const int* in_sizes, int n_in,
                              void* d_out, int out_size, void* d_ws,
                              size_t ws_size, hipStream_t stream) {
  (void)in_sizes; (void)n_in; (void)out_size; (void)ws_size;
  const float* x     = (const float*)d_in[0];  // (8,384,1024)
  const float* qkv_w = (const float*)d_in[1];  // (1024,3072)
  const float* qkv_b = (const float*)d_in[2];  // (3072,)
  const float* out_w = (const float*)d_in[3];  // (1024,1024)
  const float* out_b = (const float*)d_in[4];  // (1024,)
  const float* rpe   = (const float*)d_in[5];  // (1023,1024)

  float* out  = (float*)d_out;        // 3145728 f32
  float* attn = out + 3145728;        // 18874368 f32 (probs, written by attn3)

  unsigned short* ws  = (unsigned short*)d_ws;
  unsigned short* xb  = ws;                 // 3072*1024
  unsigned short* Wt  = xb + 3145728;       // 3072*1024 (qkv_w^T)
  unsigned short* Wot = Wt + 3145728;       // 1024*1024 (out_w^T)
  unsigned short* Tb  = Wot + 1048576;      // 1023*1024
  unsigned short* Qb  = Tb + 1047552;       // (b,h,s,hd)
  unsigned short* Kb  = Qb + 3145728;       // (b,h,s,hd) pre-scaled by 1/8
  unsigned short* Vt  = Kb + 3145728;       // (b,h,hd,s)  transposed V
  unsigned short* Vals = Vt + 3145728;      // (b*s, 1024) bf16
  unsigned short* Bias = Vals + 3145728;    // (b,h,s,s) bf16 staged XL bias

  // 1) fused prep (casts + transposes)
  prep_kernel<<<8191, 256, 0, stream>>>(x, rpe, qkv_w, out_w, xb, Tb, Wt, Wot);

  // 2) QKV projection (M=3072, N=3072); V transposed, K pre-scaled
  gemm_bt_kernel<0><<<dim3(24, 24), 256, 0, stream>>>(xb, Wt, qkv_b, Qb, Kb, Vt, nullptr);

  // 3) XL relative bias (MFMA, b-shared) -> bf16 workspace
  bias_kernel<<<dim3(16, 24, 3), 512, 0, stream>>>(Qb, Tb, Bias);

  // 4) fused QK^T(+bias) -> softmax -> PV, 32 rows/block, 8 waves
  attn3_kernel<<<dim3(128, 12), 512, 0, stream>>>(Qb, Kb, Vt, Bias, attn, Vals);

  // 5) output projection (M=3072, N=1024)
  gemm_bt_kernel<1><<<dim3(24, 8), 256, 0, stream>>>(Vals, Wot, out_b, nullptr, nullptr, nullptr, out);
}